// Round 4
// baseline (1047.795 us; speedup 1.0000x reference)
//
#include <hip/hip_runtime.h>
#include <hip/hip_bf16.h>

// QuantizedLinear: out[m,o] = sum_k x[m,k] * (q[o,k]-z[o,g])*s[o,g] + b[o]
// M=8192, K=4096, N=11008. Pass1: dequant W->bf16, cvt x->bf16 (d_ws).
// Pass2: 256x256 bf16 GEMM. A staged in LDS (dbuf, T2 swizzle, gload_lds w16);
// B loaded global->registers directly (wave-exclusive columns, no LDS round-trip).
// 1 barrier per K-tile, counted vmcnt(8) (4 A-stages drained, 8 B-loads in flight).
// T1 XCD swizzle, T5 setprio.

#define K_DIM 4096
#define N_DIM 11008
#define M_DIM 8192
#define NGRP 32

typedef __bf16 bf16x8 __attribute__((ext_vector_type(8)));
typedef float f32x4 __attribute__((ext_vector_type(4)));
typedef unsigned short u16x8 __attribute__((ext_vector_type(8)));

__device__ __forceinline__ unsigned short f2bf(float f) {
  unsigned u = __builtin_bit_cast(unsigned, f);
  return (unsigned short)((u + 0x7FFFu + ((u >> 16) & 1u)) >> 16);  // RNE
}

__device__ __forceinline__ void gload_lds16(const void* g, void* l) {
  __builtin_amdgcn_global_load_lds(
      (const __attribute__((address_space(1))) unsigned int*)(unsigned long long)g,
      (__attribute__((address_space(3))) unsigned int*)(unsigned int)(unsigned long long)l,
      16, 0, 0);
}

// ---- pass 1a: x fp32 -> bf16 ----
__global__ __launch_bounds__(256) void cvt_x_kernel(const float4* __restrict__ x4,
                                                    u16x8* __restrict__ xb) {
  int i = blockIdx.x * 256 + threadIdx.x;
  float4 a = x4[2 * i], b = x4[2 * i + 1];
  u16x8 r;
  r[0] = f2bf(a.x); r[1] = f2bf(a.y); r[2] = f2bf(a.z); r[3] = f2bf(a.w);
  r[4] = f2bf(b.x); r[5] = f2bf(b.y); r[6] = f2bf(b.z); r[7] = f2bf(b.w);
  xb[i] = r;
}

// ---- pass 1b: dequant W -> bf16 ----
__global__ __launch_bounds__(256) void dequant_kernel(const int4* __restrict__ q4,
                                                      const float* __restrict__ scales,
                                                      const float* __restrict__ zeros,
                                                      u16x8* __restrict__ wb) {
  int t = blockIdx.x * 256 + threadIdx.x;
  int o = t >> 9;
  int j8 = t & 511;
  int g = j8 >> 4;
  float s = scales[o * NGRP + g];
  float z = zeros[o * NGRP + g];
  float nzs = -z * s;
  int4 qa = q4[2 * t], qb = q4[2 * t + 1];
  u16x8 r;
  r[0] = f2bf(fmaf((float)qa.x, s, nzs));
  r[1] = f2bf(fmaf((float)qa.y, s, nzs));
  r[2] = f2bf(fmaf((float)qa.z, s, nzs));
  r[3] = f2bf(fmaf((float)qa.w, s, nzs));
  r[4] = f2bf(fmaf((float)qb.x, s, nzs));
  r[5] = f2bf(fmaf((float)qb.y, s, nzs));
  r[6] = f2bf(fmaf((float)qb.z, s, nzs));
  r[7] = f2bf(fmaf((float)qb.w, s, nzs));
  wb[t] = r;
}

// ---- pass 2: 256x256 bf16 GEMM, A in LDS dbuf, B in registers ----
// LDS: sA[2 buf][2 half][128*64] = 64 KiB. 8 waves (2M x 4N), wave tile 128x64.
// Per K-tile: READ A0 | stage A(t+1) both halves | MFMA q0,q1 | LOAD B(t+1)->regs
//             | READ A1 | MFMA q2,q3 | vmcnt(8) | barrier.
// vmcnt(8): in-flight = 4 A-stages (oldest) + 8 B-loads -> drains exactly A.

#define BAR() __builtin_amdgcn_s_barrier()
#define SCHED0() __builtin_amdgcn_sched_barrier(0)

__global__ __launch_bounds__(512, 2) void gemm_kernel(const unsigned short* __restrict__ A,
                                                      const unsigned short* __restrict__ B,
                                                      const float* __restrict__ bias,
                                                      float* __restrict__ C) {
  extern __shared__ unsigned short smem[];
  unsigned short* s0 = smem;           // buf0: [2 half][8192]
  unsigned short* s1 = smem + 16384;   // buf1

  const int bid = blockIdx.x;
  // T1: 1376 blocks, 1376 % 8 == 0 -> simple bijective XCD swizzle.
  const int swz = (bid & 7) * 172 + (bid >> 3);
  const int tm = swz / 43, tn = swz % 43;

  const int tid = threadIdx.x;
  const int w = tid >> 6, l = tid & 63;
  const int wr = w >> 2, wc = w & 3;

  const int dsto = w * 512 + l * 8;            // LDS elem offset (wave base + lane*16B)
  const int gs = (l & 7) ^ (l >> 3);           // inverse T2 swizzle on global source slot
  const unsigned short* gA = A + (size_t)(tm * 256 + (tid >> 3)) * K_DIM + gs * 8;

#define STG_A(tt, h, dst)                                                       \
  do {                                                                          \
    const unsigned short* _s = gA + (size_t)(h) * 128 * K_DIM + (tt) * 64;      \
    gload_lds16(_s, (dst) + dsto);                                              \
    gload_lds16(_s + 64 * K_DIM, (dst) + 4096 + dsto);                          \
  } while (0)

  // fragment read coords (16x16x32: lane row=l&15, k-chunk=l>>4, swizzled 16B slots)
  const int fr = l & 15, sb = l >> 4, x7 = l & 7;
  const int abase = (wr * 64 + fr) * 64;
  const int k0 = (sb ^ x7) * 8;
  const int k1 = ((sb + 4) ^ x7) * 8;

  // B direct-from-global per-lane base: col = tn*256 + wc*32 + fr, k-chunk = sb*8
  const unsigned short* gBbase = B + (size_t)(tn * 256 + wc * 32 + fr) * K_DIM + sb * 8;

  bf16x8 av[4][2];
  bf16x8 bE[2][2][2], bO[2][2][2];  // [half][nn][kk]
  f32x4 acc[8][4] = {};

#define READ_A(half)                                                     \
  {                                                                      \
    _Pragma("unroll") for (int m = 0; m < 4; ++m) {                      \
      av[m][0] = *(const bf16x8*)((half) + abase + m * 1024 + k0);       \
      av[m][1] = *(const bf16x8*)((half) + abase + m * 1024 + k1);       \
    }                                                                    \
  }
#define LOAD_B(dst, kp)                                                            \
  {                                                                                \
    _Pragma("unroll") for (int h = 0; h < 2; ++h)                                  \
    _Pragma("unroll") for (int nn = 0; nn < 2; ++nn)                               \
    _Pragma("unroll") for (int kk = 0; kk < 2; ++kk)                               \
      dst[h][nn][kk] = *(const bf16x8*)((kp) + (size_t)h * (128 * K_DIM) +         \
                                        nn * (16 * K_DIM) + kk * 32);              \
  }
#define MFMA_Q(mh, h, B2)                                                          \
  {                                                                                \
    __builtin_amdgcn_s_setprio(1);                                                 \
    _Pragma("unroll") for (int kk = 0; kk < 2; ++kk)                               \
    _Pragma("unroll") for (int m = 0; m < 4; ++m)                                  \
    _Pragma("unroll") for (int nn = 0; nn < 2; ++nn)                               \
      acc[(mh)*4 + m][(h)*2 + nn] = __builtin_amdgcn_mfma_f32_16x16x32_bf16(       \
          av[m][kk], B2[nn][kk], acc[(mh)*4 + m][(h)*2 + nn], 0, 0, 0);            \
    __builtin_amdgcn_s_setprio(0);                                                 \
  }

  // ---- prologue: stage A(0), load B(0) ----
  STG_A(0, 0, s0);
  STG_A(0, 1, s0 + 8192);
  SCHED0();
  LOAD_B(bE, gBbase);
  asm volatile("s_waitcnt vmcnt(8)" ::: "memory");
  BAR();
  SCHED0();

  const unsigned short* kp = gBbase;  // k-pointer for next-tile loads (tile index via offsets)
  for (int tt = 0; tt < 32; ++tt) {
    const int t1 = 2 * tt + 1;

    // ---- even tile t0 = 2*tt: A from s0, B = bE; prefetch t1 ----
    READ_A(s0);
    STG_A(t1, 0, s1);
    STG_A(t1, 1, s1 + 8192);
    SCHED0();
    MFMA_Q(0, 0, bE[0]);
    MFMA_Q(0, 1, bE[1]);
    SCHED0();
    LOAD_B(bO, kp + 64);
    SCHED0();
    READ_A(s0 + 8192);
    MFMA_Q(1, 1, bE[1]);
    MFMA_Q(1, 0, bE[0]);
    asm volatile("s_waitcnt vmcnt(8)" ::: "memory");
    BAR();
    SCHED0();

    // ---- odd tile t1: A from s1, B = bO; prefetch t1+1 (if any) ----
    READ_A(s1);
    if (tt < 31) {
      STG_A(t1 + 1, 0, s0);
      STG_A(t1 + 1, 1, s0 + 8192);
    }
    SCHED0();
    MFMA_Q(0, 0, bO[0]);
    MFMA_Q(0, 1, bO[1]);
    SCHED0();
    if (tt < 31) LOAD_B(bE, kp + 128);
    SCHED0();
    READ_A(s1 + 8192);
    MFMA_Q(1, 1, bO[1]);
    MFMA_Q(1, 0, bO[0]);
    if (tt < 31) {
      asm volatile("s_waitcnt vmcnt(8)" ::: "memory");
      BAR();
      SCHED0();
    }
    kp += 128;
  }

  // ---- epilogue: C/D layout col=lane&15, row=(lane>>4)*4+reg ----
  const int r0 = tm * 256 + wr * 64 + sb * 4;
  const int c0 = tn * 256 + wc * 32 + fr;
#pragma unroll
  for (int n = 0; n < 4; ++n) {
    const int col = c0 + (n >> 1) * 128 + (n & 1) * 16;
    const float bv = bias[col];
#pragma unroll
    for (int mi = 0; mi < 8; ++mi) {
      const int row = r0 + (mi >> 2) * 128 + (mi & 3) * 16;
#pragma unroll
      for (int jj = 0; jj < 4; ++jj)
        C[(size_t)(row + jj) * N_DIM + col] = acc[mi][n][jj] + bv;
    }
  }
}

extern "C" void kernel_launch(void* const* d_in, const int* in_sizes, int n_in,
                              void* d_out, int out_size, void* d_ws, size_t ws_size,
                              hipStream_t stream) {
  const float* x = (const float*)d_in[0];
  const int* qw = (const int*)d_in[1];
  const float* sc = (const float*)d_in[2];
  const float* zr = (const float*)d_in[3];
  const float* bs = (const float*)d_in[4];
  float* out = (float*)d_out;

  const size_t xb_bytes = (size_t)M_DIM * K_DIM * 2;
  const size_t wb_bytes = (size_t)N_DIM * K_DIM * 2;
  if (ws_size < xb_bytes + wb_bytes) return;

  unsigned short* xb = (unsigned short*)d_ws;
  unsigned short* wb = (unsigned short*)((char*)d_ws + xb_bytes);

  (void)hipFuncSetAttribute((const void*)gemm_kernel,
                            hipFuncAttributeMaxDynamicSharedMemorySize, 65536);

  cvt_x_kernel<<<(M_DIM * K_DIM / 8) / 256, 256, 0, stream>>>((const float4*)x, (u16x8*)xb);
  dequant_kernel<<<(N_DIM * K_DIM / 8) / 256, 256, 0, stream>>>((const int4*)qw, sc, zr,
                                                                (u16x8*)wb);
  gemm_kernel<<<(M_DIM / 256) * (N_DIM / 256), 512, 65536, stream>>>(xb, wb, bs, out);
}

// Round 5
// 831.742 us; speedup vs baseline: 1.2598x; 1.2598x over previous
//
#include <hip/hip_runtime.h>
#include <hip/hip_bf16.h>

// QuantizedLinear: out[m,o] = sum_k x[m,k] * (q[o,k]-z[o,g])*s[o,g] + b[o]
// M=8192, K=4096, N=11008.
// Pass1: cvt x->bf16; dequant W->bf16 in FRAGMENT-LINEAR layout:
//   piece(n16, kc, kk) holds a 16-col x 32-k MFMA B-fragment; lane l (fr=l&15,
//   sb=l>>4) owns col=n16*16+fr, k=kc*64+kk*32+sb*8..+7 at byte
//   ((n16*64+kc)*2+kk)*1024 + l*16. GEMM B-loads are coalesced 1KB/wave.
// Pass2: 256x256 bf16 GEMM. A staged in LDS (dbuf, T2 swizzle, gload_lds w16);
// B loaded global->registers (wave-exclusive columns). 1 barrier per K-tile,
// counted vmcnt(8). T1 XCD swizzle, T5 setprio.

#define K_DIM 4096
#define N_DIM 11008
#define M_DIM 8192
#define NGRP 32
#define KC_N 64  // K_DIM/64

typedef __bf16 bf16x8 __attribute__((ext_vector_type(8)));
typedef float f32x4 __attribute__((ext_vector_type(4)));
typedef unsigned short u16x8 __attribute__((ext_vector_type(8)));

__device__ __forceinline__ unsigned short f2bf(float f) {
  unsigned u = __builtin_bit_cast(unsigned, f);
  return (unsigned short)((u + 0x7FFFu + ((u >> 16) & 1u)) >> 16);  // RNE
}

__device__ __forceinline__ void gload_lds16(const void* g, void* l) {
  __builtin_amdgcn_global_load_lds(
      (const __attribute__((address_space(1))) unsigned int*)(unsigned long long)g,
      (__attribute__((address_space(3))) unsigned int*)(unsigned int)(unsigned long long)l,
      16, 0, 0);
}

// ---- pass 1a: x fp32 -> bf16 ----
__global__ __launch_bounds__(256) void cvt_x_kernel(const float4* __restrict__ x4,
                                                    u16x8* __restrict__ xb) {
  int i = blockIdx.x * 256 + threadIdx.x;
  float4 a = x4[2 * i], b = x4[2 * i + 1];
  u16x8 r;
  r[0] = f2bf(a.x); r[1] = f2bf(a.y); r[2] = f2bf(a.z); r[3] = f2bf(a.w);
  r[4] = f2bf(b.x); r[5] = f2bf(b.y); r[6] = f2bf(b.z); r[7] = f2bf(b.w);
  xb[i] = r;
}

// ---- pass 1b: dequant W -> bf16, fragment-linear. One wave per 16x64 subtile. ----
__global__ __launch_bounds__(256) void dequant_fl_kernel(const int* __restrict__ q,
                                                         const float* __restrict__ scales,
                                                         const float* __restrict__ zeros,
                                                         u16x8* __restrict__ wb) {
  const int st = blockIdx.x * 4 + (threadIdx.x >> 6);  // subtile id, < 688*64
  const int l = threadIdx.x & 63;
  const int n16 = st >> 6;   // / KC_N
  const int kc = st & 63;
  const int col = n16 * 16 + (l & 15);
  const int sb = l >> 4;
  const int g = kc >> 1;     // 64-k chunk -> group of 128
  const float s = scales[col * NGRP + g];
  const float z = zeros[col * NGRP + g];
  const float nzs = -z * s;
  const int* qp = q + (size_t)col * K_DIM + kc * 64 + sb * 8;
#pragma unroll
  for (int kk = 0; kk < 2; ++kk) {
    const int4 qa = *(const int4*)(qp + kk * 32);
    const int4 qb = *(const int4*)(qp + kk * 32 + 4);
    u16x8 r;
    r[0] = f2bf(fmaf((float)qa.x, s, nzs));
    r[1] = f2bf(fmaf((float)qa.y, s, nzs));
    r[2] = f2bf(fmaf((float)qa.z, s, nzs));
    r[3] = f2bf(fmaf((float)qa.w, s, nzs));
    r[4] = f2bf(fmaf((float)qb.x, s, nzs));
    r[5] = f2bf(fmaf((float)qb.y, s, nzs));
    r[6] = f2bf(fmaf((float)qb.z, s, nzs));
    r[7] = f2bf(fmaf((float)qb.w, s, nzs));
    wb[(size_t)(st * 2 + kk) * 64 + l] = r;  // coalesced 1KB/wave store
  }
}

// ---- pass 2: 256x256 bf16 GEMM, A in LDS dbuf, B in registers (frag-linear) ----
// LDS: sA[2 buf][2 half][128*64] = 64 KiB. 8 waves (2M x 4N), wave tile 128x64.
// Per K-tile: READ A0 | stage A(t+1) | MFMA q0,q1 | LOAD B(t+1) | READ A1 |
//             MFMA q2,q3 | vmcnt(8) | barrier.
// vmcnt(8): in-flight = 4 A-stages (oldest) + 8 B-loads -> drains exactly A.

#define BAR() __builtin_amdgcn_s_barrier()
#define SCHED0() __builtin_amdgcn_sched_barrier(0)

__global__ __launch_bounds__(512, 2) void gemm_kernel(const unsigned short* __restrict__ A,
                                                      const unsigned short* __restrict__ B,
                                                      const float* __restrict__ bias,
                                                      float* __restrict__ C) {
  extern __shared__ unsigned short smem[];
  unsigned short* s0 = smem;           // buf0: [2 half][8192]
  unsigned short* s1 = smem + 16384;   // buf1

  const int bid = blockIdx.x;
  // T1: 1376 blocks, 1376 % 8 == 0 -> simple bijective XCD swizzle.
  const int swz = (bid & 7) * 172 + (bid >> 3);
  const int tm = swz / 43, tn = swz % 43;

  const int tid = threadIdx.x;
  const int w = tid >> 6, l = tid & 63;
  const int wr = w >> 2, wc = w & 3;

  const int dsto = w * 512 + l * 8;            // LDS elem offset (wave base + lane*16B)
  const int gs = (l & 7) ^ (l >> 3);           // inverse T2 swizzle on global source slot
  const unsigned short* gA = A + (size_t)(tm * 256 + (tid >> 3)) * K_DIM + gs * 8;

#define STG_A(tt, h, dst)                                                       \
  do {                                                                          \
    const unsigned short* _s = gA + (size_t)(h) * 128 * K_DIM + (tt) * 64;      \
    gload_lds16(_s, (dst) + dsto);                                              \
    gload_lds16(_s + 64 * K_DIM, (dst) + 4096 + dsto);                          \
  } while (0)

  // A fragment read coords (16x16x32: lane row=l&15, k-chunk=l>>4, swizzled slots)
  const int fr = l & 15, sb = l >> 4, x7 = l & 7;
  const int abase = (wr * 64 + fr) * 64;
  const int k0 = (sb ^ x7) * 8;
  const int k1 = ((sb + 4) ^ x7) * 8;

  // B fragment-linear per-lane base: n16 stride = 8192 bf16x8 units (16KB... 8192*16B=128KB)
  const bf16x8* gB0 = (const bf16x8*)B + (size_t)(tn * 16 + wc * 2) * 8192 + l;

  bf16x8 av[4][2];
  bf16x8 bE[2][2][2], bO[2][2][2];  // [half][nn][kk]
  f32x4 acc[8][4] = {};

#define READ_A(half)                                                     \
  {                                                                      \
    _Pragma("unroll") for (int m = 0; m < 4; ++m) {                      \
      av[m][0] = *(const bf16x8*)((half) + abase + m * 1024 + k0);       \
      av[m][1] = *(const bf16x8*)((half) + abase + m * 1024 + k1);       \
    }                                                                    \
  }
// coalesced: piece (h,nn,kk) of K-tile kc at gB0 + (h*8+nn)*8192 + kc*128 + kk*64
#define LOAD_B(dst, kc)                                                            \
  {                                                                                \
    _Pragma("unroll") for (int h = 0; h < 2; ++h)                                  \
    _Pragma("unroll") for (int nn = 0; nn < 2; ++nn)                               \
    _Pragma("unroll") for (int kk = 0; kk < 2; ++kk)                               \
      dst[h][nn][kk] = gB0[(h * 8 + nn) * 8192 + (kc) * 128 + kk * 64];            \
  }
#define MFMA_Q(mh, h, B2)                                                          \
  {                                                                                \
    __builtin_amdgcn_s_setprio(1);                                                 \
    _Pragma("unroll") for (int kk = 0; kk < 2; ++kk)                               \
    _Pragma("unroll") for (int m = 0; m < 4; ++m)                                  \
    _Pragma("unroll") for (int nn = 0; nn < 2; ++nn)                               \
      acc[(mh)*4 + m][(h)*2 + nn] = __builtin_amdgcn_mfma_f32_16x16x32_bf16(       \
          av[m][kk], B2[nn][kk], acc[(mh)*4 + m][(h)*2 + nn], 0, 0, 0);            \
    __builtin_amdgcn_s_setprio(0);                                                 \
  }

  // ---- prologue: stage A(0), load B(0) ----
  STG_A(0, 0, s0);
  STG_A(0, 1, s0 + 8192);
  SCHED0();
  LOAD_B(bE, 0);
  asm volatile("s_waitcnt vmcnt(8)" ::: "memory");
  BAR();
  SCHED0();

  for (int tt = 0; tt < 32; ++tt) {
    // ---- even tile 2*tt: A from s0, B = bE; prefetch 2*tt+1 ----
    READ_A(s0);
    STG_A(2 * tt + 1, 0, s1);
    STG_A(2 * tt + 1, 1, s1 + 8192);
    SCHED0();
    MFMA_Q(0, 0, bE[0]);
    MFMA_Q(0, 1, bE[1]);
    SCHED0();
    LOAD_B(bO, 2 * tt + 1);
    SCHED0();
    READ_A(s0 + 8192);
    MFMA_Q(1, 1, bE[1]);
    MFMA_Q(1, 0, bE[0]);
    asm volatile("s_waitcnt vmcnt(8)" ::: "memory");
    BAR();
    SCHED0();

    // ---- odd tile 2*tt+1: A from s1, B = bO; prefetch 2*tt+2 ----
    READ_A(s1);
    if (tt < 31) {
      STG_A(2 * tt + 2, 0, s0);
      STG_A(2 * tt + 2, 1, s0 + 8192);
    }
    SCHED0();
    MFMA_Q(0, 0, bO[0]);
    MFMA_Q(0, 1, bO[1]);
    SCHED0();
    if (tt < 31) LOAD_B(bE, 2 * tt + 2);
    SCHED0();
    READ_A(s1 + 8192);
    MFMA_Q(1, 1, bO[1]);
    MFMA_Q(1, 0, bO[0]);
    if (tt < 31) {
      asm volatile("s_waitcnt vmcnt(8)" ::: "memory");
      BAR();
      SCHED0();
    }
  }

  // ---- epilogue: C/D layout col=lane&15, row=(lane>>4)*4+reg ----
  const int r0 = tm * 256 + wr * 64 + sb * 4;
  const int c0 = tn * 256 + wc * 32 + fr;
#pragma unroll
  for (int n = 0; n < 4; ++n) {
    const int col = c0 + (n >> 1) * 128 + (n & 1) * 16;
    const float bv = bias[col];
#pragma unroll
    for (int mi = 0; mi < 8; ++mi) {
      const int row = r0 + (mi >> 2) * 128 + (mi & 3) * 16;
#pragma unroll
      for (int jj = 0; jj < 4; ++jj)
        C[(size_t)(row + jj) * N_DIM + col] = acc[mi][n][jj] + bv;
    }
  }
}

extern "C" void kernel_launch(void* const* d_in, const int* in_sizes, int n_in,
                              void* d_out, int out_size, void* d_ws, size_t ws_size,
                              hipStream_t stream) {
  const float* x = (const float*)d_in[0];
  const int* qw = (const int*)d_in[1];
  const float* sc = (const float*)d_in[2];
  const float* zr = (const float*)d_in[3];
  const float* bs = (const float*)d_in[4];
  float* out = (float*)d_out;

  const size_t xb_bytes = (size_t)M_DIM * K_DIM * 2;
  const size_t wb_bytes = (size_t)N_DIM * K_DIM * 2;
  if (ws_size < xb_bytes + wb_bytes) return;

  unsigned short* xb = (unsigned short*)d_ws;
  unsigned short* wb = (unsigned short*)((char*)d_ws + xb_bytes);

  (void)hipFuncSetAttribute((const void*)gemm_kernel,
                            hipFuncAttributeMaxDynamicSharedMemorySize, 65536);

  cvt_x_kernel<<<(M_DIM * K_DIM / 8) / 256, 256, 0, stream>>>((const float4*)x, (u16x8*)xb);
  dequant_fl_kernel<<<(N_DIM / 16) * KC_N / 4, 256, 0, stream>>>(qw, sc, zr, (u16x8*)wb);
  gemm_kernel<<<(M_DIM / 256) * (N_DIM / 256), 512, 65536, stream>>>(xb, wb, bs, out);
}

// Round 6
// 708.357 us; speedup vs baseline: 1.4792x; 1.1742x over previous
//
#include <hip/hip_runtime.h>
#include <hip/hip_bf16.h>

// QuantizedLinear: out[m,o] = sum_k x[m,k] * (q[o,k]-z[o,g])*s[o,g] + b[o]
// M=8192, K=4096, N=11008. Pass1: dequant W->bf16 (row-major B^T), cvt x->bf16.
// Pass2: 256x256 bf16 GEMM, TWO phases per K-tile (merged from R3's four):
//  P1: read A0,B0,B1 | stage A1,B0(t+1)->nxt | MFMA (0,0),(0,1) | BAR1
//  P2: read A1 | stage A0,B1(t+2)->cur | MFMA (1,1),(1,0) | vmcnt(4) | BAR2
// BAR1 guards P2's cur-writes vs P1's cur-reads; vmcnt(4) drains tile t+1.
// T1 XCD swizzle, T2 LDS swizzle (inverse-swizzled global source), T5 setprio.

#define K_DIM 4096
#define N_DIM 11008
#define M_DIM 8192
#define NGRP 32

typedef __bf16 bf16x8 __attribute__((ext_vector_type(8)));
typedef float f32x4 __attribute__((ext_vector_type(4)));
typedef unsigned short u16x8 __attribute__((ext_vector_type(8)));

__device__ __forceinline__ unsigned short f2bf(float f) {
  unsigned u = __builtin_bit_cast(unsigned, f);
  return (unsigned short)((u + 0x7FFFu + ((u >> 16) & 1u)) >> 16);  // RNE
}

__device__ __forceinline__ void gload_lds16(const void* g, void* l) {
  __builtin_amdgcn_global_load_lds(
      (const __attribute__((address_space(1))) unsigned int*)(unsigned long long)g,
      (__attribute__((address_space(3))) unsigned int*)(unsigned int)(unsigned long long)l,
      16, 0, 0);
}

// ---- pass 1a: x fp32 -> bf16 ----
__global__ __launch_bounds__(256) void cvt_x_kernel(const float4* __restrict__ x4,
                                                    u16x8* __restrict__ xb) {
  int i = blockIdx.x * 256 + threadIdx.x;
  float4 a = x4[2 * i], b = x4[2 * i + 1];
  u16x8 r;
  r[0] = f2bf(a.x); r[1] = f2bf(a.y); r[2] = f2bf(a.z); r[3] = f2bf(a.w);
  r[4] = f2bf(b.x); r[5] = f2bf(b.y); r[6] = f2bf(b.z); r[7] = f2bf(b.w);
  xb[i] = r;
}

// ---- pass 1b: dequant W -> bf16 (row-major [N][K]) ----
__global__ __launch_bounds__(256) void dequant_kernel(const int4* __restrict__ q4,
                                                      const float* __restrict__ scales,
                                                      const float* __restrict__ zeros,
                                                      u16x8* __restrict__ wb) {
  int t = blockIdx.x * 256 + threadIdx.x;
  int o = t >> 9;
  int j8 = t & 511;
  int g = j8 >> 4;
  float s = scales[o * NGRP + g];
  float z = zeros[o * NGRP + g];
  float nzs = -z * s;
  int4 qa = q4[2 * t], qb = q4[2 * t + 1];
  u16x8 r;
  r[0] = f2bf(fmaf((float)qa.x, s, nzs));
  r[1] = f2bf(fmaf((float)qa.y, s, nzs));
  r[2] = f2bf(fmaf((float)qa.z, s, nzs));
  r[3] = f2bf(fmaf((float)qa.w, s, nzs));
  r[4] = f2bf(fmaf((float)qb.x, s, nzs));
  r[5] = f2bf(fmaf((float)qb.y, s, nzs));
  r[6] = f2bf(fmaf((float)qb.z, s, nzs));
  r[7] = f2bf(fmaf((float)qb.w, s, nzs));
  wb[t] = r;
}

// ---- pass 2: 256x256 bf16 GEMM, 2 phases / K-tile ----
#define BAR() __builtin_amdgcn_s_barrier()
#define SCHED0() __builtin_amdgcn_sched_barrier(0)

__global__ __launch_bounds__(512, 2) void gemm_kernel(const unsigned short* __restrict__ A,
                                                      const unsigned short* __restrict__ B,
                                                      const float* __restrict__ bias,
                                                      float* __restrict__ C) {
  extern __shared__ unsigned short smem[];
  unsigned short* sAb = smem;           // [2 buf][2 half][8192]
  unsigned short* sBb = smem + 32768;

  const int bid = blockIdx.x;
  // T1: 1376 blocks, 1376 % 8 == 0 -> simple bijective XCD swizzle.
  const int swz = (bid & 7) * 172 + (bid >> 3);
  const int tm = swz / 43, tn = swz % 43;

  const int tid = threadIdx.x;
  const int w = tid >> 6, l = tid & 63;
  const int wr = w >> 2, wc = w & 3;

  const int dsto = w * 512 + l * 8;            // LDS elem offset (wave base + lane*16B)
  const int gs = (l & 7) ^ (l >> 3);           // inverse T2 swizzle on global source slot
  const unsigned short* gA = A + (size_t)(tm * 256 + (tid >> 3)) * K_DIM + gs * 8;
  const unsigned short* gB = B + (size_t)(tn * 256 + (tid >> 3)) * K_DIM + gs * 8;

#define STG_A(tt, h, dst)                                                       \
  do {                                                                          \
    const unsigned short* _s = gA + (size_t)(h) * 128 * K_DIM + (tt) * 64;      \
    gload_lds16(_s, (dst) + dsto);                                              \
    gload_lds16(_s + 64 * K_DIM, (dst) + 4096 + dsto);                          \
  } while (0)
#define STG_B(tt, h, dst)                                                       \
  do {                                                                          \
    const unsigned short* _s = gB + (size_t)(h) * 128 * K_DIM + (tt) * 64;      \
    gload_lds16(_s, (dst) + dsto);                                              \
    gload_lds16(_s + 4096 + dsto);                                              \
  } while (0)

  // NOTE: careful — STG_B second line must mirror STG_A (fixed below by using
  // identical macro body; see STG_B2). Kept single definition for safety:
#undef STG_B
#define STG_B(tt, h, dst)                                                       \
  do {                                                                          \
    const unsigned short* _s = gB + (size_t)(h) * 128 * K_DIM + (tt) * 64;      \
    gload_lds16(_s, (dst) + dsto);                                              \
    gload_lds16(_s + 64 * K_DIM, (dst) + 4096 + dsto);                          \
  } while (0)

  // fragment read coords (16x16x32: lane row=l&15, k-chunk=l>>4, swizzled slots)
  const int fr = l & 15, sb = l >> 4, x7 = l & 7;
  const int abase = (wr * 64 + fr) * 64;
  const int bbase = (wc * 32 + fr) * 64;
  const int k0 = (sb ^ x7) * 8;
  const int k1 = ((sb + 4) ^ x7) * 8;

  bf16x8 av[4][2], bva[2][2], bvb[2][2];
  f32x4 acc[8][4] = {};

#define READ_A(half)                                                     \
  {                                                                      \
    _Pragma("unroll") for (int m = 0; m < 4; ++m) {                      \
      av[m][0] = *(const bf16x8*)((half) + abase + m * 1024 + k0);       \
      av[m][1] = *(const bf16x8*)((half) + abase + m * 1024 + k1);       \
    }                                                                    \
  }
#define READ_B(half, arr)                                                \
  {                                                                      \
    _Pragma("unroll") for (int n = 0; n < 2; ++n) {                      \
      arr[n][0] = *(const bf16x8*)((half) + bbase + n * 1024 + k0);      \
      arr[n][1] = *(const bf16x8*)((half) + bbase + n * 1024 + k1);      \
    }                                                                    \
  }
#define MFMA_Q(mh, nh, arr)                                                        \
  {                                                                                \
    __builtin_amdgcn_s_setprio(1);                                                 \
    _Pragma("unroll") for (int kk = 0; kk < 2; ++kk)                               \
    _Pragma("unroll") for (int m = 0; m < 4; ++m)                                  \
    _Pragma("unroll") for (int nn = 0; nn < 2; ++nn)                               \
      acc[(mh)*4 + m][(nh)*2 + nn] = __builtin_amdgcn_mfma_f32_16x16x32_bf16(      \
          av[m][kk], arr[nn][kk], acc[(mh)*4 + m][(nh)*2 + nn], 0, 0, 0);          \
    __builtin_amdgcn_s_setprio(0);                                                 \
  }

  // ---- prologue: tile0 all 4 halves + A0(1), B1(1) into buf1 ----
  STG_A(0, 0, sAb);
  STG_A(0, 1, sAb + 8192);
  STG_B(0, 0, sBb);
  STG_B(0, 1, sBb + 8192);
  STG_A(1, 0, sAb + 16384);
  STG_B(1, 1, sBb + 16384 + 8192);
  asm volatile("s_waitcnt vmcnt(4)" ::: "memory");
  BAR();
  SCHED0();

  for (int tt = 0; tt < 32; ++tt) {
    // ======== even tile t = 2*tt (cur = buf0, nxt = buf1) ========
    // P1: read A0,B0,B1; stage A1(t+1),B0(t+1)->nxt; MFMA (0,0),(0,1)
    READ_A(sAb);
    READ_B(sBb, bva);
    READ_B(sBb + 8192, bvb);
    STG_A(2 * tt + 1, 1, sAb + 16384 + 8192);
    STG_B(2 * tt + 1, 0, sBb + 16384);
    MFMA_Q(0, 0, bva);
    MFMA_Q(0, 1, bvb);
    SCHED0();
    BAR();
    SCHED0();
    // P2: read A1; stage A0(t+2),B1(t+2)->cur; MFMA (1,1),(1,0)
    READ_A(sAb + 8192);
    if (tt < 31) {
      STG_A(2 * tt + 2, 0, sAb);
      STG_B(2 * tt + 2, 1, sBb + 8192);
    }
    MFMA_Q(1, 1, bvb);
    MFMA_Q(1, 0, bva);
    if (tt < 31) {
      asm volatile("s_waitcnt vmcnt(4)" ::: "memory");
    } else {
      asm volatile("s_waitcnt vmcnt(0)" ::: "memory");
    }
    BAR();
    SCHED0();

    // ======== odd tile t = 2*tt+1 (cur = buf1, nxt = buf0) ========
    // P1: read A0,B0,B1; stage A1(t+1),B0(t+1)->buf0; MFMA (0,0),(0,1)
    READ_A(sAb + 16384);
    READ_B(sBb + 16384, bva);
    READ_B(sBb + 16384 + 8192, bvb);
    if (tt < 31) {
      STG_A(2 * tt + 2, 1, sAb + 8192);
      STG_B(2 * tt + 2, 0, sBb);
    }
    MFMA_Q(0, 0, bva);
    MFMA_Q(0, 1, bvb);
    SCHED0();
    BAR();
    SCHED0();
    // P2: read A1; stage A0(t+2),B1(t+2)->buf1; MFMA (1,1),(1,0)
    READ_A(sAb + 16384 + 8192);
    if (tt < 31) {
      STG_A(2 * tt + 3, 0, sAb + 16384);
      STG_B(2 * tt + 3, 1, sBb + 16384 + 8192);
    }
    MFMA_Q(1, 1, bvb);
    MFMA_Q(1, 0, bva);
    if (tt < 31) {
      asm volatile("s_waitcnt vmcnt(4)" ::: "memory");
      BAR();
      SCHED0();
    }
  }

  // ---- epilogue: C/D layout col=lane&15, row=(lane>>4)*4+reg ----
  const int r0 = tm * 256 + wr * 64 + sb * 4;
  const int c0 = tn * 256 + wc * 32 + fr;
#pragma unroll
  for (int n = 0; n < 4; ++n) {
    const int col = c0 + (n >> 1) * 128 + (n & 1) * 16;
    const float bv = bias[col];
#pragma unroll
    for (int mi = 0; mi < 8; ++mi) {
      const int row = r0 + (mi >> 2) * 128 + (mi & 3) * 16;
#pragma unroll
      for (int jj = 0; jj < 4; ++jj)
        C[(size_t)(row + jj) * N_DIM + col] = acc[mi][n][jj] + bv;
    }
  }
}

extern "C" void kernel_launch(void* const* d_in, const int* in_sizes, int n_in,
                              void* d_out, int out_size, void* d_ws, size_t ws_size,
                              hipStream_t stream) {
  const float* x = (const float*)d_in[0];
  const int* qw = (const int*)d_in[1];
  const float* sc = (const float*)d_in[2];
  const float* zr = (const float*)d_in[3];
  const float* bs = (const float*)d_in[4];
  float* out = (float*)d_out;

  const size_t xb_bytes = (size_t)M_DIM * K_DIM * 2;
  const size_t wb_bytes = (size_t)N_DIM * K_DIM * 2;
  if (ws_size < xb_bytes + wb_bytes) return;

  unsigned short* xb = (unsigned short*)d_ws;
  unsigned short* wb = (unsigned short*)((char*)d_ws + xb_bytes);

  (void)hipFuncSetAttribute((const void*)gemm_kernel,
                            hipFuncAttributeMaxDynamicSharedMemorySize, 131072);

  cvt_x_kernel<<<(M_DIM * K_DIM / 8) / 256, 256, 0, stream>>>((const float4*)x, (u16x8*)xb);
  dequant_kernel<<<(N_DIM * K_DIM / 8) / 256, 256, 0, stream>>>((const int4*)qw, sc, zr,
                                                                (u16x8*)wb);
  gemm_kernel<<<(M_DIM / 256) * (N_DIM / 256), 512, 131072, stream>>>(xb, wb, bs, out);
}